// Round 4
// baseline (207.351 us; speedup 1.0000x reference)
//
#include <hip/hip_runtime.h>
#include <math.h>

// FNOGeoEncoder — exact algebraic reduction (only the DC mode survives the
// final mean):
//   S       = sum_t V[t,:]                           (3,)
//   X0[c]   = fc0_w[c,:].S + N*fc0_b[c]              (256,)
//   X_{k+1} = Re(sc_w[k,:,:,0])^T X_k                (4 matvecs 256x256)
//   z       = tanh((X4/N)@fc1_w^T + fc1_b)@fc2_w^T + fc2_b
//
// Measured floor: the mode-0 gather (262144 lines at 4096-B stride) is
// DRAM-transaction-bound at ~30 us. This version keeps all gathered
// weights IN REGISTERS, hides vsum+lift under the gather (careful vmcnt
// ordering: V issued before w's; S published via packed fixed-point u64
// atomics so no fence touches the gather waves), and runs the 4-layer
// chain via atomicAdd + device-scope spin barriers. One zero kernel +
// one fused kernel.

constexpr int kN = 131072;

#define SCOPE __HIP_MEMORY_SCOPE_AGENT

// ws byte layout:
//   0     u64 S_fixed[3]        packed: (count<<52) | fixed24(sum+16384*1024)
//   64    u32 cnt[i] at 64+64*i, i = 1..5
//   640   u32 x0rdy
//   704   f32 X0[256]
//   1728  f32 X[4][256]         (X1..X4, atomicAdd targets)
//   5824  f32 H[128]
//   6336  f32 scratch[64]       (keep-alive sink, unread)

__global__ __launch_bounds__(256) void k_zero(float* ws) {
  int t = threadIdx.x;
  #pragma unroll
  for (int i = 0; i < 7; ++i) {
    int idx = t + i * 256;
    if (idx < 1600) ws[idx] = 0.f;
  }
}

__device__ __forceinline__ unsigned ld_u32(const unsigned* p) {
  return __hip_atomic_load(p, __ATOMIC_ACQUIRE, SCOPE);
}

__global__ __launch_bounds__(256) void fused(const float* __restrict__ V,
                                             const float* __restrict__ sc_w,
                                             const float* __restrict__ fc0_w,
                                             const float* __restrict__ fc0_b,
                                             const float* __restrict__ fc1_w,
                                             const float* __restrict__ fc1_b,
                                             const float* __restrict__ fc2_w,
                                             const float* __restrict__ fc2_b,
                                             float* __restrict__ out,
                                             float* __restrict__ ws) {
  unsigned long long* S_fixed = (unsigned long long*)ws;
  unsigned* cnt    = (unsigned*)((char*)ws + 64);    // counter i at cnt[i*16]
  unsigned* x0rdy  = (unsigned*)((char*)ws + 640);
  float* X0 = (float*)((char*)ws + 704);
  float* X  = (float*)((char*)ws + 1728);            // X1..X4
  float* H  = (float*)((char*)ws + 5824);
  float* scr = (float*)((char*)ws + 6336);

  const int b = blockIdx.x, t = threadIdx.x;
  __shared__ float lds[256];
  __shared__ float xbc;
  __shared__ double Sd[3];

  if (b == 256) {
    // ---- reducer + IF$ warmer (holds no scattered loads) ----
    const float4* f1 = (const float4*)fc1_w;   // 8192 float4
    const float4* f2 = (const float4*)fc2_w;   // 8192 float4
    float acc = 0.f;
    for (int i = t; i < 8192; i += 256) {
      float4 a = f1[i], c = f2[i];
      acc += a.x + a.y + a.z + a.w + c.x + c.y + c.z + c.w;
    }
    scr[t & 63] = acc;  // keep loads alive (racy, never read)
    if (t == 0) {
      for (int j = 0; j < 3; ++j) {
        unsigned long long v; int guard = 0;
        do {
          v = __hip_atomic_load(&S_fixed[j], __ATOMIC_ACQUIRE, SCOPE);
        } while ((v >> 52) < 1024ull && ++guard < (1 << 22));
        long long fixed = (long long)(v & ((1ull << 52) - 1ull));
        Sd[j] = (double)fixed * (1.0 / 16777216.0) - 1024.0 * 16384.0;
      }
    }
    __syncthreads();
    float x0 = (float)(Sd[0] * (double)fc0_w[t * 3] +
                       Sd[1] * (double)fc0_w[t * 3 + 1] +
                       Sd[2] * (double)fc0_w[t * 3 + 2]) +
               (float)kN * fc0_b[t];
    __hip_atomic_store(&X0[t], x0, __ATOMIC_RELEASE, SCOPE);
    __syncthreads();
    if (t == 0) __hip_atomic_store(x0rdy, 1u, __ATOMIC_RELEASE, SCOPE);
    return;
  }

  // ---- gather blocks: c = b, o = t ----
  const int gid = b * 256 + t;

  // 1) V loads FIRST (oldest in vmcnt order -> consumable without draining w's)
  const float4* Vf4 = (const float4*)V;
  float4 v0 = Vf4[gid];
  float4 v1 = make_float4(0.f, 0.f, 0.f, 0.f);
  if (b < 128) v1 = Vf4[65536 + gid];   // covers float4 65536..98303

  // 2) the scattered gather (4 loads, 4096-B stride, 256-MB layer stride)
  const size_t base = (size_t)gid * 1024;
  const size_t lstr = (size_t)65536 * 1024;
  float w0 = sc_w[base];
  float w1 = sc_w[base + lstr];
  float w2 = sc_w[base + 2 * lstr];
  float w3 = sc_w[base + 3 * lstr];

  // 3) vsum: per-wave shuffle reduce (no __syncthreads -> w's stay in flight)
  int r0 = gid % 3;                       // component of v0.x (4q mod 3 = q mod 3)
  float xx = v0.x + v0.w, yy = v0.y, zz = v0.z;
  float s0, s1, s2;
  if (r0 == 0)      { s0 = xx; s1 = yy; s2 = zz; }
  else if (r0 == 1) { s0 = zz; s1 = xx; s2 = yy; }
  else              { s0 = yy; s1 = zz; s2 = xx; }
  int r1 = (r0 + 1) % 3;                  // 65536 % 3 == 1
  float xx2 = v1.x + v1.w, yy2 = v1.y, zz2 = v1.z;
  if (r1 == 0)      { s0 += xx2; s1 += yy2; s2 += zz2; }
  else if (r1 == 1) { s0 += zz2; s1 += xx2; s2 += yy2; }
  else              { s0 += yy2; s1 += zz2; s2 += xx2; }
  #pragma unroll
  for (int off = 32; off > 0; off >>= 1) {
    s0 += __shfl_down(s0, off, 64);
    s1 += __shfl_down(s1, off, 64);
    s2 += __shfl_down(s2, off, 64);
  }
  if ((t & 63) == 0) {
    // packed fixed-point publish: arrival count in bits 52+, value below.
    // v' = s + 16384 > 0; fixed = round(v' * 2^24) < 2^38; 1024 adds < 2^48.
    unsigned long long p0 = (1ull << 52) +
        (unsigned long long)((double)s0 * 16777216.0 + 274877906944.0 + 0.5);
    unsigned long long p1 = (1ull << 52) +
        (unsigned long long)((double)s1 * 16777216.0 + 274877906944.0 + 0.5);
    unsigned long long p2 = (1ull << 52) +
        (unsigned long long)((double)s2 * 16777216.0 + 274877906944.0 + 0.5);
    __hip_atomic_fetch_add(&S_fixed[0], p0, __ATOMIC_RELAXED, SCOPE);
    __hip_atomic_fetch_add(&S_fixed[1], p1, __ATOMIC_RELAXED, SCOPE);
    __hip_atomic_fetch_add(&S_fixed[2], p2, __ATOMIC_RELAXED, SCOPE);
  }

  // 4) wait for X0 (this spin's vmcnt(0) IS phase-0's natural wait for w's)
  if (t == 0) {
    int guard = 0;
    while (ld_u32(x0rdy) < 1u && ++guard < (1 << 22)) {}
    xbc = __hip_atomic_load(&X0[b], __ATOMIC_ACQUIRE, SCOPE);
  }
  __syncthreads();
  float xv = xbc;

  // 5) 4-layer chain: atomicAdd + spin barrier per layer
  atomicAdd(&X[0 * 256 + t], w0 * xv);
  __syncthreads();                                   // drains this block's adds
  if (t == 0) {
    __hip_atomic_fetch_add(&cnt[1 * 16], 1u, __ATOMIC_ACQ_REL, SCOPE);
    int guard = 0;
    while (ld_u32(&cnt[1 * 16]) < 256u && ++guard < (1 << 22)) {}
    xbc = __hip_atomic_load(&X[0 * 256 + b], __ATOMIC_ACQUIRE, SCOPE);
  }
  __syncthreads();
  xv = xbc;

  atomicAdd(&X[1 * 256 + t], w1 * xv);
  __syncthreads();
  if (t == 0) {
    __hip_atomic_fetch_add(&cnt[2 * 16], 1u, __ATOMIC_ACQ_REL, SCOPE);
    int guard = 0;
    while (ld_u32(&cnt[2 * 16]) < 256u && ++guard < (1 << 22)) {}
    xbc = __hip_atomic_load(&X[1 * 256 + b], __ATOMIC_ACQUIRE, SCOPE);
  }
  __syncthreads();
  xv = xbc;

  atomicAdd(&X[2 * 256 + t], w2 * xv);
  __syncthreads();
  if (t == 0) {
    __hip_atomic_fetch_add(&cnt[3 * 16], 1u, __ATOMIC_ACQ_REL, SCOPE);
    int guard = 0;
    while (ld_u32(&cnt[3 * 16]) < 256u && ++guard < (1 << 22)) {}
    xbc = __hip_atomic_load(&X[2 * 256 + b], __ATOMIC_ACQUIRE, SCOPE);
  }
  __syncthreads();
  xv = xbc;

  atomicAdd(&X[3 * 256 + t], w3 * xv);
  __syncthreads();
  if (t == 0) {
    __hip_atomic_fetch_add(&cnt[4 * 16], 1u, __ATOMIC_ACQ_REL, SCOPE);
    int guard = 0;
    while (ld_u32(&cnt[4 * 16]) < 256u && ++guard < (1 << 22)) {}
  }
  __syncthreads();

  // 6) head. fc1 by blocks 0..127 (weights IF$-warm via reducer block)
  if (b < 128) {
    float fv = __hip_atomic_load(&X[3 * 256 + t], __ATOMIC_ACQUIRE, SCOPE) *
               (1.0f / (float)kN);
    lds[t] = fv * fc1_w[b * 256 + t];
    __syncthreads();
    #pragma unroll
    for (int off = 128; off > 0; off >>= 1) {
      if (t < off) lds[t] += lds[t + off];
      __syncthreads();
    }
    if (t == 0) {
      float hj = tanhf(lds[0] + fc1_b[b]);
      __hip_atomic_store(&H[b], hj, __ATOMIC_RELEASE, SCOPE);
      __hip_atomic_fetch_add(&cnt[5 * 16], 1u, __ATOMIC_ACQ_REL, SCOPE);
    }
  }

  // fc2 by all 256 blocks (output k = b)
  if (t == 0) {
    int guard = 0;
    while (ld_u32(&cnt[5 * 16]) < 128u && ++guard < (1 << 22)) {}
  }
  __syncthreads();
  float pv = 0.f;
  if (t < 128) {
    float hv = __hip_atomic_load(&H[t], __ATOMIC_ACQUIRE, SCOPE);
    pv = hv * fc2_w[b * 128 + t];
  }
  lds[t] = pv;
  __syncthreads();
  #pragma unroll
  for (int off = 128; off > 0; off >>= 1) {
    if (t < off) lds[t] += lds[t + off];
    __syncthreads();
  }
  if (t == 0) out[b] = lds[0] + fc2_b[b];
}

extern "C" void kernel_launch(void* const* d_in, const int* in_sizes, int n_in,
                              void* d_out, int out_size, void* d_ws, size_t ws_size,
                              hipStream_t stream) {
  const float* V     = (const float*)d_in[0];
  const float* fc0_w = (const float*)d_in[1];
  const float* fc0_b = (const float*)d_in[2];
  const float* sc_w  = (const float*)d_in[3];
  const float* fc1_w = (const float*)d_in[4];
  const float* fc1_b = (const float*)d_in[5];
  const float* fc2_w = (const float*)d_in[6];
  const float* fc2_b = (const float*)d_in[7];
  float* out = (float*)d_out;
  float* ws = (float*)d_ws;

  k_zero<<<1, 256, 0, stream>>>(ws);
  fused<<<257, 256, 0, stream>>>(V, sc_w, fc0_w, fc0_b, fc1_w, fc1_b,
                                 fc2_w, fc2_b, out, ws);
}

// Round 5
// 37.107 us; speedup vs baseline: 5.5879x; 5.5879x over previous
//
#include <hip/hip_runtime.h>
#include <math.h>

// FNOGeoEncoder — exact algebraic reduction (only DC mode survives the mean):
//   S       = sum_t V[t,:]                          (3,)
//   X0[c]   = fc0_w[c,:].S + N*fc0_b[c]             (256,)
//   X_{k+1} = Re(sc_w[k,:,:,0])^T X_k               (4 matvecs 256x256)
//   feat    = X4 / N
//   z       = tanh(feat@fc1_w^T + fc1_b)@fc2_w^T + fc2_b
//
// Structure: the scattered mode-0 weight gather is chain-independent, so
// stage A (full GPU) compacts it + computes V partial sums; stage B (one
// block) runs the whole serial chain through LDS-synced stages.
//
// Measured cost decomposition (r1-r4):
//  - gather: 262144 lines at 4096-B-aligned stride = ~30 us, DRAM
//    bank/channel-conflict-bound; invariant across 3 issue structures.
//  - tail: ~6 us, conserved across {1-CU stream, 4 launches, 8-block
//    flag-sync} — serial 4-layer dependency x cross-CU visibility.
//  - cross-block single-counter barriers are ~20 us each (r4): never again.

constexpr int kN = 131072;
constexpr int kWidth = 256;
constexpr int kModes = 512;
constexpr int kLayers = 4;
constexpr size_t kLayerStride = (size_t)kWidth * kWidth * kModes * 2;  // floats
constexpr int kGatherBlocks = 256;   // 256 blk * 256 thr * 4 layers = 262144 gathers
constexpr int kVsumBlocks = 384;     // 384 blk * 256 thr * 1 float4 = 98304 = 131072*3/4

// ws layout (floats):
//   [0, 262144)            compact W[l][c][o]
//   [262144, 262144+1152)  vsum partials [384][3]

__global__ __launch_bounds__(256) void stageA(const float* __restrict__ sc_w,
                                              const float* __restrict__ V,
                                              float* __restrict__ ws) {
    int b = blockIdx.x, t = threadIdx.x;
    if (b < kGatherBlocks) {
        int rem = b * 256 + t;  // flat (c,o), 0..65535; consecutive t -> consecutive o
        const float* src = sc_w + (size_t)rem * (size_t)(kModes * 2);
        #pragma unroll
        for (int l = 0; l < kLayers; ++l) {
            ws[(size_t)l * 65536 + rem] = src[(size_t)l * kLayerStride];
        }
    } else {
        int vb = b - kGatherBlocks;
        int q = vb * 256 + t;  // float4 index, 0..98303
        const float4 v = reinterpret_cast<const float4*>(V)[q];
        int r = q % 3;         // component of first element (f=4q, f%3 == q%3)
        float a[3] = {0.f, 0.f, 0.f};
        a[r] = v.x + v.w;
        a[(r + 1) % 3] = v.y;
        a[(r + 2) % 3] = v.z;
        __shared__ float sred[3][256];
        sred[0][t] = a[0]; sred[1][t] = a[1]; sred[2][t] = a[2];
        __syncthreads();
        for (int off = 128; off > 0; off >>= 1) {
            if (t < off) {
                sred[0][t] += sred[0][t + off];
                sred[1][t] += sred[1][t + off];
                sred[2][t] += sred[2][t + off];
            }
            __syncthreads();
        }
        if (t == 0) {
            float* partials = ws + 262144;
            partials[vb * 3 + 0] = sred[0][0];
            partials[vb * 3 + 1] = sred[1][0];
            partials[vb * 3 + 2] = sred[2][0];
        }
    }
}

__global__ __launch_bounds__(1024) void stageB(const float* __restrict__ ws,
                                               const float* __restrict__ fc0_w,
                                               const float* __restrict__ fc0_b,
                                               const float* __restrict__ fc1_w,
                                               const float* __restrict__ fc1_b,
                                               const float* __restrict__ fc2_w,
                                               const float* __restrict__ fc2_b,
                                               float* __restrict__ out) {
    __shared__ float red[1024];
    __shared__ float xbuf[256];
    __shared__ float part[4][256];
    __shared__ float S[3];
    __shared__ float hbuf[128];
    int t = threadIdx.x;
    const float* partials = ws + 262144;

    // S[j] = fixed-order tree sum of partials[384][j]
    for (int j = 0; j < 3; ++j) {
        red[t] = (t < kVsumBlocks) ? partials[t * 3 + j] : 0.f;
        __syncthreads();
        for (int off = 512; off > 0; off >>= 1) {
            if (t < off) red[t] += red[t + off];
            __syncthreads();
        }
        if (t == 0) S[j] = red[0];
        __syncthreads();
    }

    // lift at DC
    if (t < 256) {
        xbuf[t] = S[0] * fc0_w[t * 3] + S[1] * fc0_w[t * 3 + 1] +
                  S[2] * fc0_w[t * 3 + 2] + (float)kN * fc0_b[t];
    }
    __syncthreads();

    // 4 spectral-DC matvecs, split-K by 4 wave-groups
    int g = t >> 8, o = t & 255;
    for (int l = 0; l < kLayers; ++l) {
        const float* W = ws + (size_t)l * 65536;
        float acc = 0.f;
        int c0 = g * 64;
        #pragma unroll 8
        for (int i = 0; i < 64; ++i) {
            int c = c0 + i;
            acc += W[c * 256 + o] * xbuf[c];  // coalesced across o per iteration
        }
        part[g][o] = acc;
        __syncthreads();
        if (t < 256) xbuf[t] = part[0][t] + part[1][t] + part[2][t] + part[3][t];
        __syncthreads();
    }

    // feat = X4 / N
    if (t < 256) xbuf[t] *= (1.0f / (float)kN);
    __syncthreads();

    // fc1 + tanh: 128 outputs, split-K by 8
    {
        int j = t & 127, s = t >> 7;
        float acc = 0.f;
        int c0 = s * 32;
        #pragma unroll 8
        for (int i = 0; i < 32; ++i) acc += xbuf[c0 + i] * fc1_w[j * 256 + c0 + i];
        red[s * 128 + j] = acc;
        __syncthreads();
        if (t < 128) {
            float a = 0.f;
            #pragma unroll
            for (int s2 = 0; s2 < 8; ++s2) a += red[s2 * 128 + t];
            hbuf[t] = tanhf(a + fc1_b[t]);
        }
        __syncthreads();
    }

    // fc2: 256 outputs, split-K by 4
    {
        int k = t & 255, s = t >> 8;
        float acc = 0.f;
        int c0 = s * 32;
        #pragma unroll 8
        for (int i = 0; i < 32; ++i) acc += hbuf[c0 + i] * fc2_w[k * 128 + c0 + i];
        red[s * 256 + k] = acc;
        __syncthreads();
        if (t < 256) out[t] = red[t] + red[256 + t] + red[512 + t] + red[768 + t] + fc2_b[t];
    }
}

extern "C" void kernel_launch(void* const* d_in, const int* in_sizes, int n_in,
                              void* d_out, int out_size, void* d_ws, size_t ws_size,
                              hipStream_t stream) {
    const float* V     = (const float*)d_in[0];
    const float* fc0_w = (const float*)d_in[1];
    const float* fc0_b = (const float*)d_in[2];
    const float* sc_w  = (const float*)d_in[3];
    const float* fc1_w = (const float*)d_in[4];
    const float* fc1_b = (const float*)d_in[5];
    const float* fc2_w = (const float*)d_in[6];
    const float* fc2_b = (const float*)d_in[7];
    float* out = (float*)d_out;
    float* ws = (float*)d_ws;

    stageA<<<kGatherBlocks + kVsumBlocks, 256, 0, stream>>>(sc_w, V, ws);
    stageB<<<1, 1024, 0, stream>>>(ws, fc0_w, fc0_b, fc1_w, fc1_b, fc2_w, fc2_b, out);
}